// Round 4
// baseline (300.574 us; speedup 1.0000x reference)
//
#include <hip/hip_runtime.h>
#include <hip/hip_bf16.h>

// MHA forward: B=4, S=1024, D=1024, H=16, DK=64
// outputs: out [4,1024,1024] f32, attn [4,16,1024,1024] f32 (concat in d_out)

typedef __bf16 bf16_t;
typedef __bf16 bf16x4 __attribute__((ext_vector_type(4)));
typedef __bf16 bf16x8 __attribute__((ext_vector_type(8)));
typedef float f32x4 __attribute__((ext_vector_type(4)));

#define MFMA16(a, b, c) __builtin_amdgcn_mfma_f32_16x16x32_bf16(a, b, c, 0, 0, 0)

// ---------------------------------------------------------------- cast x -> bf16
__global__ __launch_bounds__(256) void cast_f32_bf16(const float* __restrict__ in,
                                                     bf16_t* __restrict__ out, int n4) {
    int i = blockIdx.x * blockDim.x + threadIdx.x;
    if (i >= n4) return;
    float4 v = reinterpret_cast<const float4*>(in)[i];
    bf16x4 o = { (bf16_t)v.x, (bf16_t)v.y, (bf16_t)v.z, (bf16_t)v.w };
    reinterpret_cast<bf16x4*>(out)[i] = o;
}

// ------------------------------------------- transpose + cast the 4 weight matrices
__global__ __launch_bounds__(1024) void transpose_cast_w(const float* __restrict__ w0,
                                                         const float* __restrict__ w1,
                                                         const float* __restrict__ w2,
                                                         const float* __restrict__ w3,
                                                         bf16_t* __restrict__ wt) {
    __shared__ float tile[32][33];
    const float* src = (blockIdx.z == 0) ? w0 : (blockIdx.z == 1) ? w1
                     : (blockIdx.z == 2) ? w2 : w3;
    bf16_t* dst = wt + (size_t)blockIdx.z * 1024 * 1024;
    int r0 = blockIdx.y * 32, c0 = blockIdx.x * 32;
    tile[threadIdx.y][threadIdx.x] = src[(size_t)(r0 + threadIdx.y) * 1024 + c0 + threadIdx.x];
    __syncthreads();
    dst[(size_t)(c0 + threadIdx.y) * 1024 + r0 + threadIdx.x] = (bf16_t)tile[threadIdx.x][threadIdx.y];
}

// ---------------------------------------------------- LDS-tiled NT GEMM, 128x128 tile
// A: [4096,1024] bf16 row-major; BT: [1024,1024] bf16 row-major ([N][K])
// block = 256 threads = 4 waves (2x2), each wave 64x64 output (4x4 frags of 16x16)
// BK=32. LDS XOR-swizzled in 16B slots: slot' = slot ^ ((row>>1)&3).
template <int MODE>
__global__ __launch_bounds__(256, 3) void gemm_tile(const bf16_t* __restrict__ A,
                                                    const bf16_t* __restrict__ BT,
                                                    void* __restrict__ out) {
    __shared__ bf16_t As[128 * 32];
    __shared__ bf16_t Bs[128 * 32];
    const int tid = threadIdx.x;
    const int lane = tid & 63, wave = tid >> 6;
    const int lr = lane & 15, lg = lane >> 4;
    const int m_base = blockIdx.x * 128, n_base = blockIdx.y * 128;
    const int wm = (wave >> 1) * 64, wn = (wave & 1) * 64;

    // staging: each thread stages 1 row x 2 slots of As and of Bs
    const int srow = tid >> 1;              // 0..127
    const int sl0 = (tid & 1) * 2;          // 0 or 2
    const int sl1 = sl0 + 1;
    const int off0 = srow * 32 + ((sl0 ^ ((srow >> 1) & 3)) * 8);
    const int off1 = srow * 32 + ((sl1 ^ ((srow >> 1) & 3)) * 8);

    const bf16_t* aptr = A + (size_t)(m_base + srow) * 1024 + sl0 * 8;
    const bf16_t* bptr = BT + (size_t)(n_base + srow) * 1024 + sl0 * 8;

    bf16x8 ra0 = *reinterpret_cast<const bf16x8*>(aptr);
    bf16x8 ra1 = *reinterpret_cast<const bf16x8*>(aptr + 8);
    bf16x8 rb0 = *reinterpret_cast<const bf16x8*>(bptr);
    bf16x8 rb1 = *reinterpret_cast<const bf16x8*>(bptr + 8);

    f32x4 acc[4][4] = {};
    for (int kb = 32; kb <= 1024; kb += 32) {
        __syncthreads();
        *reinterpret_cast<bf16x8*>(&As[off0]) = ra0;
        *reinterpret_cast<bf16x8*>(&As[off1]) = ra1;
        *reinterpret_cast<bf16x8*>(&Bs[off0]) = rb0;
        *reinterpret_cast<bf16x8*>(&Bs[off1]) = rb1;
        if (kb < 1024) {
            ra0 = *reinterpret_cast<const bf16x8*>(aptr + kb);
            ra1 = *reinterpret_cast<const bf16x8*>(aptr + kb + 8);
            rb0 = *reinterpret_cast<const bf16x8*>(bptr + kb);
            rb1 = *reinterpret_cast<const bf16x8*>(bptr + kb + 8);
        }
        __syncthreads();
        bf16x8 af[4], bfr[4];
#pragma unroll
        for (int i = 0; i < 4; ++i) {
            const int row = wm + i * 16 + lr;
            af[i] = *reinterpret_cast<const bf16x8*>(&As[row * 32 + ((lg ^ ((row >> 1) & 3)) * 8)]);
        }
#pragma unroll
        for (int j = 0; j < 4; ++j) {
            const int row = wn + j * 16 + lr;
            bfr[j] = *reinterpret_cast<const bf16x8*>(&Bs[row * 32 + ((lg ^ ((row >> 1) & 3)) * 8)]);
        }
#pragma unroll
        for (int i = 0; i < 4; ++i)
#pragma unroll
            for (int j = 0; j < 4; ++j)
                acc[i][j] = MFMA16(af[i], bfr[j], acc[i][j]);
    }

#pragma unroll
    for (int i = 0; i < 4; ++i)
#pragma unroll
        for (int j = 0; j < 4; ++j)
#pragma unroll
            for (int r = 0; r < 4; ++r) {
                const int row = m_base + wm + i * 16 + lg * 4 + r;
                const int col = n_base + wn + j * 16 + lr;
                const float v = acc[i][j][r];
                if (MODE == 0) {
                    ((bf16_t*)out)[(size_t)row * 1024 + col] = (bf16_t)(v * 0.125f);
                } else if (MODE == 1) {
                    ((bf16_t*)out)[(size_t)row * 1024 + col] = (bf16_t)v;
                } else if (MODE == 2) {
                    const int bb = row >> 10, s = row & 1023, hh = col >> 6, d = col & 63;
                    ((bf16_t*)out)[(((size_t)(bb * 16 + hh) * 64 + d) << 10) + s] = (bf16_t)v;
                } else {
                    ((float*)out)[(size_t)row * 1024 + col] = v;
                }
            }
}

// --------------------------------------- fused scores+bias+softmax+attn-write+PV
// SWAPPED QK^T: S^T = mfma(K, Q) -> lane owns ONE q-row (q = lane&15) with
// k = f*16 + lg*4 + reg: 4 consecutive k per frag -> f32x4 bias loads, f32x4
// attn stores, ds_write_b64 P-pack. Softmax = in-lane reduce + 2 shuffles +
// tiny LDS. P -> swizzled per-wave LDS tile -> PV MFMA (A=P, B=V^T rows).
// LDS exactly 32 KB (smax/ssum aliased) -> 5 blocks/CU.
__global__ __launch_bounds__(256, 5) void fused_attn(const bf16_t* __restrict__ qb,
                                                     const bf16_t* __restrict__ kbuf,
                                                     const bf16_t* __restrict__ vt,
                                                     const float* __restrict__ bias,
                                                     float* __restrict__ attn,
                                                     bf16_t* __restrict__ ctxb) {
    __shared__ bf16_t plds[4][16][256];     // 32768 B: per-wave 16x256 P tile
    const int lane = threadIdx.x & 63;
    const int wave = threadIdx.x >> 6;
    const int lr = lane & 15, lg = lane >> 4;

    // decode: g&7 = xcd slot; per-xcd order: b fastest (shares bias tile), then qt
    const int g = blockIdx.x;
    const int j = g >> 3;
    const int h = (g & 7) + 8 * (j >> 8);
    const int qt = (j & 255) >> 2;
    const int b = j & 3;
    const int bh = b * 16 + h;
    const int m0 = qt * 16;

    // Q fragment (B-operand of swapped MFMA): lane holds Q[m0+lr][dk lg*8..+7]
    const bf16_t* qp = qb + ((size_t)b << 20) + (size_t)(m0 + lr) * 1024 + h * 64 + lg * 8;
    const bf16x8 aq0 = *reinterpret_cast<const bf16x8*>(qp);
    const bf16x8 aq1 = *reinterpret_cast<const bf16x8*>(qp + 32);

    const int c0 = wave * 256;              // this wave's k-col slice
    const bf16_t* kbase = kbuf + ((size_t)b << 20) + h * 64 + lg * 8;
    const float* brow = bias + ((size_t)h << 20) + (size_t)(m0 + lr) * 1024 + c0 + lg * 4;

    // ---- QK^T (swapped) + bias; S^T stays in registers: acc[f][r] =
    //      S[q = m0+lr][k = c0 + f*16 + lg*4 + r]
    f32x4 acc[16];
#pragma unroll
    for (int f = 0; f < 16; ++f) acc[f] = (f32x4){0.f, 0.f, 0.f, 0.f};

#pragma unroll
    for (int f = 0; f < 16; ++f) {
        const bf16_t* kp = kbase + (size_t)(c0 + f * 16 + lr) * 1024;
        bf16x8 k0 = *reinterpret_cast<const bf16x8*>(kp);
        bf16x8 k1 = *reinterpret_cast<const bf16x8*>(kp + 32);
        acc[f] = MFMA16(k0, aq0, acc[f]);       // A = K rows, B = Q rows -> S^T
        acc[f] = MFMA16(k1, aq1, acc[f]);
        f32x4 bv = *reinterpret_cast<const f32x4*>(brow + f * 16);
        acc[f] += bv;
    }

    float* smaxp = reinterpret_cast<float*>(&plds[0][0][0]);   // 64 f32 (aliased)
    float* ssump = smaxp + 64;                                 // 64 f32 (aliased)

    // ---- row max: in-lane over 64 values, shuffle xor16/32, LDS cross-wave
    f32x4 m4 = acc[0];
#pragma unroll
    for (int f = 1; f < 16; ++f) {
#pragma unroll
        for (int r = 0; r < 4; ++r) m4[r] = fmaxf(m4[r], acc[f][r]);
    }
    float mx = fmaxf(fmaxf(m4[0], m4[1]), fmaxf(m4[2], m4[3]));
    mx = fmaxf(mx, __shfl_xor(mx, 16));
    mx = fmaxf(mx, __shfl_xor(mx, 32));
    if (lane < 16) smaxp[wave * 16 + lr] = mx;
    __syncthreads();
    const float gm = fmaxf(fmaxf(smaxp[lr], smaxp[16 + lr]),
                           fmaxf(smaxp[32 + lr], smaxp[48 + lr]));

    // ---- exp once + row sum
    f32x4 s4 = {0.f, 0.f, 0.f, 0.f};
#pragma unroll
    for (int f = 0; f < 16; ++f) {
#pragma unroll
        for (int r = 0; r < 4; ++r) {
            const float e = __expf(acc[f][r] - gm);
            acc[f][r] = e;
            s4[r] += e;
        }
    }
    float sm = (s4[0] + s4[1]) + (s4[2] + s4[3]);
    sm += __shfl_xor(sm, 16);
    sm += __shfl_xor(sm, 32);
    if (lane < 16) ssump[wave * 16 + lr] = sm;
    __syncthreads();
    const float invl = 1.0f / (ssump[lr] + ssump[16 + lr] + ssump[32 + lr] + ssump[48 + lr]);
    __syncthreads();   // guard: smax/ssum alias the P region written below

    // ---- write normalized attn (f32x4) + pack P to swizzled LDS (b64)
    float* orow = attn + ((size_t)bh << 20) + (size_t)(m0 + lr) * 1024 + c0 + lg * 4;
    char* pw = reinterpret_cast<char*>(&plds[wave][0][0]);
    const int swz = (lr & 7) << 4;
#pragma unroll
    for (int f = 0; f < 16; ++f) {
        f32x4 v = acc[f];
#pragma unroll
        for (int r = 0; r < 4; ++r) v[r] *= invl;
        *reinterpret_cast<f32x4*>(orow + f * 16) = v;
        bf16x4 pb = { (bf16_t)v[0], (bf16_t)v[1], (bf16_t)v[2], (bf16_t)v[3] };
        *reinterpret_cast<bf16x4*>(pw + lr * 512 + ((f * 32 + lg * 8) ^ swz)) = pb;
    }
    // (no barrier: plds[wave] is written and read only by this wave; the
    //  compiler orders same-array LDS accesses with lgkmcnt)

    // ---- PV over this wave's 256 cols: A = P[q][k] (LDS), B = V^T rows (vt)
    const bf16_t* vb = vt + (size_t)bh * (64 * 1024) + c0 + lg * 8;
    f32x4 cacc[4];
#pragma unroll
    for (int f2 = 0; f2 < 4; ++f2) cacc[f2] = (f32x4){0.f, 0.f, 0.f, 0.f};
#pragma unroll
    for (int ks = 0; ks < 8; ++ks) {
        bf16x8 pa = *reinterpret_cast<const bf16x8*>(pw + lr * 512 + ((ks * 64 + lg * 16) ^ swz));
#pragma unroll
        for (int f2 = 0; f2 < 4; ++f2) {
            bf16x8 vf = *reinterpret_cast<const bf16x8*>(vb + (size_t)(f2 * 16 + lr) * 1024 + ks * 32);
            cacc[f2] = MFMA16(pa, vf, cacc[f2]);
        }
    }
    __syncthreads();   // all waves done with P tiles; re-alias as cred

    // ---- cross-wave ctx reduce via LDS (aliases plds)
    float* cred = reinterpret_cast<float*>(&plds[0][0][0]);    // [4][16][64] f32
#pragma unroll
    for (int f2 = 0; f2 < 4; ++f2)
#pragma unroll
        for (int r = 0; r < 4; ++r)
            cred[wave * 1024 + (lg * 4 + r) * 64 + f2 * 16 + lr] = cacc[f2][r];
    __syncthreads();
    const int row_l = wave * 4 + lg;
    const int dk0 = lr * 4;
    f32x4 s0 = *reinterpret_cast<const f32x4*>(&cred[0 * 1024 + row_l * 64 + dk0]);
    f32x4 s1 = *reinterpret_cast<const f32x4*>(&cred[1 * 1024 + row_l * 64 + dk0]);
    f32x4 s2 = *reinterpret_cast<const f32x4*>(&cred[2 * 1024 + row_l * 64 + dk0]);
    f32x4 s3 = *reinterpret_cast<const f32x4*>(&cred[3 * 1024 + row_l * 64 + dk0]);
    f32x4 st = (s0 + s1) + (s2 + s3);
    bf16x4 o4 = { (bf16_t)st[0], (bf16_t)st[1], (bf16_t)st[2], (bf16_t)st[3] };
    *reinterpret_cast<bf16x4*>(
        &ctxb[(size_t)(b * 1024 + m0 + row_l) * 1024 + h * 64 + dk0]) = o4;
}

// ---------------------------------------------------------------------- launcher
extern "C" void kernel_launch(void* const* d_in, const int* in_sizes, int n_in,
                              void* d_out, int out_size, void* d_ws, size_t ws_size,
                              hipStream_t stream) {
    const float* x    = (const float*)d_in[0];
    const float* bias = (const float*)d_in[1];
    const float* Wq   = (const float*)d_in[2];
    const float* Wk   = (const float*)d_in[3];
    const float* Wv   = (const float*)d_in[4];
    const float* Wo   = (const float*)d_in[5];
    float* out  = (float*)d_out;
    float* attn = out + (size_t)4 * 1024 * 1024;

    char* ws = (char*)d_ws;
    bf16_t* xb   = (bf16_t*)(ws);                      //  8 MB [4096,1024]
    bf16_t* wT   = (bf16_t*)(ws + ((size_t)8 << 20));  //  8 MB 4x [1024,1024] transposed
    bf16_t* qb   = (bf16_t*)(ws + ((size_t)16 << 20)); //  8 MB Q/8 [B,S,D]
    bf16_t* kbuf = (bf16_t*)(ws + ((size_t)24 << 20)); //  8 MB K   [B,S,D]
    bf16_t* vt   = (bf16_t*)(ws + ((size_t)32 << 20)); //  8 MB VT  [B,H,DK,S]
    bf16_t* ctxb = (bf16_t*)(ws + ((size_t)40 << 20)); //  8 MB ctx [B,S,D]
    bf16_t* wqT = wT;
    bf16_t* wkT = wT + ((size_t)1 << 20);
    bf16_t* wvT = wT + ((size_t)2 << 20);
    bf16_t* woT = wT + ((size_t)3 << 20);

    cast_f32_bf16<<<dim3(4096), dim3(256), 0, stream>>>(x, xb, 1024 * 1024);
    transpose_cast_w<<<dim3(32, 32, 4), dim3(32, 32), 0, stream>>>(Wq, Wk, Wv, Wo, wT);

    gemm_tile<0><<<dim3(32, 8), dim3(256), 0, stream>>>(xb, wqT, qb);
    gemm_tile<1><<<dim3(32, 8), dim3(256), 0, stream>>>(xb, wkT, kbuf);
    gemm_tile<2><<<dim3(32, 8), dim3(256), 0, stream>>>(xb, wvT, vt);

    fused_attn<<<dim3(4096), dim3(256), 0, stream>>>(qb, kbuf, vt, bias, attn, ctxb);

    gemm_tile<3><<<dim3(32, 8), dim3(256), 0, stream>>>(ctxb, woT, out);
}

// Round 5
// 242.836 us; speedup vs baseline: 1.2378x; 1.2378x over previous
//
#include <hip/hip_runtime.h>
#include <hip/hip_bf16.h>

// MHA forward: B=4, S=1024, D=1024, H=16, DK=64
// outputs: out [4,1024,1024] f32, attn [4,16,1024,1024] f32 (concat in d_out)
//
// Packed operand layouts for the fused kernel (all bf16):
//   qhp/khp: [bh][half=dk/32][s][32]   -> frag loads 1KB contiguous
//   vp:      [bh][kb=s/32][dk][32]     -> PV frag loads 1KB contiguous

typedef __bf16 bf16_t;
typedef __bf16 bf16x4 __attribute__((ext_vector_type(4)));
typedef __bf16 bf16x8 __attribute__((ext_vector_type(8)));
typedef float f32x4 __attribute__((ext_vector_type(4)));

#define MFMA16(a, b, c) __builtin_amdgcn_mfma_f32_16x16x32_bf16(a, b, c, 0, 0, 0)

// ---------------------------------------------------------------- cast x -> bf16
__global__ __launch_bounds__(256) void cast_f32_bf16(const float* __restrict__ in,
                                                     bf16_t* __restrict__ out, int n4) {
    int i = blockIdx.x * blockDim.x + threadIdx.x;
    if (i >= n4) return;
    float4 v = reinterpret_cast<const float4*>(in)[i];
    bf16x4 o = { (bf16_t)v.x, (bf16_t)v.y, (bf16_t)v.z, (bf16_t)v.w };
    reinterpret_cast<bf16x4*>(out)[i] = o;
}

// ------------------------------------------- transpose + cast the 4 weight matrices
__global__ __launch_bounds__(1024) void transpose_cast_w(const float* __restrict__ w0,
                                                         const float* __restrict__ w1,
                                                         const float* __restrict__ w2,
                                                         const float* __restrict__ w3,
                                                         bf16_t* __restrict__ wt) {
    __shared__ float tile[32][33];
    const float* src = (blockIdx.z == 0) ? w0 : (blockIdx.z == 1) ? w1
                     : (blockIdx.z == 2) ? w2 : w3;
    bf16_t* dst = wt + (size_t)blockIdx.z * 1024 * 1024;
    int r0 = blockIdx.y * 32, c0 = blockIdx.x * 32;
    tile[threadIdx.y][threadIdx.x] = src[(size_t)(r0 + threadIdx.y) * 1024 + c0 + threadIdx.x];
    __syncthreads();
    dst[(size_t)(c0 + threadIdx.y) * 1024 + r0 + threadIdx.x] = (bf16_t)tile[threadIdx.x][threadIdx.y];
}

// ---------------------------------------------------- LDS-tiled NT GEMM, 128x128 tile
// block = 256 threads = 4 waves (2x2), each wave 64x64 output (4x4 frags of 16x16)
// MODE 0: Q -> qhp packed, scale 0.125   MODE 1: K -> khp packed
// MODE 2: V -> vp packed                 MODE 3: f32 row-major (out)
template <int MODE>
__global__ __launch_bounds__(256, 3) void gemm_tile(const bf16_t* __restrict__ A,
                                                    const bf16_t* __restrict__ BT,
                                                    void* __restrict__ out) {
    __shared__ bf16_t As[128 * 32];
    __shared__ bf16_t Bs[128 * 32];
    const int tid = threadIdx.x;
    const int lane = tid & 63, wave = tid >> 6;
    const int lr = lane & 15, lg = lane >> 4;
    const int m_base = blockIdx.x * 128, n_base = blockIdx.y * 128;
    const int wm = (wave >> 1) * 64, wn = (wave & 1) * 64;

    const int srow = tid >> 1;
    const int sl0 = (tid & 1) * 2;
    const int sl1 = sl0 + 1;
    const int off0 = srow * 32 + ((sl0 ^ ((srow >> 1) & 3)) * 8);
    const int off1 = srow * 32 + ((sl1 ^ ((srow >> 1) & 3)) * 8);

    const bf16_t* aptr = A + (size_t)(m_base + srow) * 1024 + sl0 * 8;
    const bf16_t* bptr = BT + (size_t)(n_base + srow) * 1024 + sl0 * 8;

    bf16x8 ra0 = *reinterpret_cast<const bf16x8*>(aptr);
    bf16x8 ra1 = *reinterpret_cast<const bf16x8*>(aptr + 8);
    bf16x8 rb0 = *reinterpret_cast<const bf16x8*>(bptr);
    bf16x8 rb1 = *reinterpret_cast<const bf16x8*>(bptr + 8);

    f32x4 acc[4][4] = {};
    for (int kb = 32; kb <= 1024; kb += 32) {
        __syncthreads();
        *reinterpret_cast<bf16x8*>(&As[off0]) = ra0;
        *reinterpret_cast<bf16x8*>(&As[off1]) = ra1;
        *reinterpret_cast<bf16x8*>(&Bs[off0]) = rb0;
        *reinterpret_cast<bf16x8*>(&Bs[off1]) = rb1;
        if (kb < 1024) {
            ra0 = *reinterpret_cast<const bf16x8*>(aptr + kb);
            ra1 = *reinterpret_cast<const bf16x8*>(aptr + kb + 8);
            rb0 = *reinterpret_cast<const bf16x8*>(bptr + kb);
            rb1 = *reinterpret_cast<const bf16x8*>(bptr + kb + 8);
        }
        __syncthreads();
        bf16x8 af[4], bfr[4];
#pragma unroll
        for (int i = 0; i < 4; ++i) {
            const int row = wm + i * 16 + lr;
            af[i] = *reinterpret_cast<const bf16x8*>(&As[row * 32 + ((lg ^ ((row >> 1) & 3)) * 8)]);
        }
#pragma unroll
        for (int j = 0; j < 4; ++j) {
            const int row = wn + j * 16 + lr;
            bfr[j] = *reinterpret_cast<const bf16x8*>(&Bs[row * 32 + ((lg ^ ((row >> 1) & 3)) * 8)]);
        }
#pragma unroll
        for (int i = 0; i < 4; ++i)
#pragma unroll
            for (int j = 0; j < 4; ++j)
                acc[i][j] = MFMA16(af[i], bfr[j], acc[i][j]);
    }

#pragma unroll
    for (int i = 0; i < 4; ++i)
#pragma unroll
        for (int j = 0; j < 4; ++j)
#pragma unroll
            for (int r = 0; r < 4; ++r) {
                const int row = m_base + wm + i * 16 + lg * 4 + r;
                const int col = n_base + wn + j * 16 + lr;
                const float v = acc[i][j][r];
                if (MODE == 3) {
                    ((float*)out)[(size_t)row * 1024 + col] = v;
                } else {
                    const int b = row >> 10, s = row & 1023;
                    const int h = col >> 6, d = col & 63;
                    const size_t bh16 = (size_t)(b * 16 + h) << 16;
                    if (MODE == 0) {
                        ((bf16_t*)out)[bh16 + ((d >> 5) << 15) + s * 32 + (d & 31)] =
                            (bf16_t)(v * 0.125f);
                    } else if (MODE == 1) {
                        ((bf16_t*)out)[bh16 + ((d >> 5) << 15) + s * 32 + (d & 31)] = (bf16_t)v;
                    } else {   // MODE 2: vp[bh][s/32][d][s%32]
                        ((bf16_t*)out)[bh16 + ((s >> 5) << 11) + d * 32 + (s & 31)] = (bf16_t)v;
                    }
                }
            }
}

// --------------------------------------- fused scores+bias+softmax+attn-write+PV
// SWAPPED QK^T: S^T = mfma(K, Q) -> lane owns ONE q-row (q = lane&15), cols
// k = f*16 + lg*4 + reg. All K/Q/V frag loads are 1KB-contiguous (packed
// layouts). Softmax in-lane + 2 shuffles + tiny LDS. P -> swizzled per-wave
// LDS tile -> PV MFMA. LDS 32KB; launch_bounds(256,4) -> 4 waves/SIMD.
__global__ __launch_bounds__(256, 4) void fused_attn(const bf16_t* __restrict__ qhp,
                                                     const bf16_t* __restrict__ khp,
                                                     const bf16_t* __restrict__ vp,
                                                     const float* __restrict__ bias,
                                                     float* __restrict__ attn,
                                                     bf16_t* __restrict__ ctxb) {
    __shared__ bf16_t plds[4][16][256];     // 32768 B: per-wave 16x256 P tile
    const int lane = threadIdx.x & 63;
    const int wave = threadIdx.x >> 6;
    const int lr = lane & 15, lg = lane >> 4;

    // decode: g&7 = xcd slot; per-xcd order: b fastest (shares bias tile), then qt
    const int g = blockIdx.x;
    const int j = g >> 3;
    const int h = (g & 7) + 8 * (j >> 8);
    const int qt = (j & 255) >> 2;
    const int b = j & 3;
    const int bh = b * 16 + h;
    const int m0 = qt * 16;

    // Q B-frag: lane holds Q[m0+lr][dk lg*8..+7] per half-plane (1KB contiguous)
    const bf16_t* qbase = qhp + ((size_t)bh << 16);
    const bf16x8 aq0 = *reinterpret_cast<const bf16x8*>(qbase + (m0 + lr) * 32 + lg * 8);
    const bf16x8 aq1 = *reinterpret_cast<const bf16x8*>(qbase + 32768 + (m0 + lr) * 32 + lg * 8);

    const int c0 = wave * 256;              // this wave's k-col slice
    const bf16_t* k0base = khp + ((size_t)bh << 16) + lg * 8;
    const bf16_t* k1base = k0base + 32768;
    const float* brow = bias + ((size_t)h << 20) + (size_t)(m0 + lr) * 1024 + c0 + lg * 4;

    // ---- QK^T (swapped) + bias: acc[f][r] = S[q=m0+lr][k=c0+f*16+lg*4+r]
    f32x4 acc[16];
#pragma unroll
    for (int f = 0; f < 16; ++f) acc[f] = (f32x4){0.f, 0.f, 0.f, 0.f};

#pragma unroll
    for (int f = 0; f < 16; ++f) {
        const int krow = c0 + f * 16 + lr;
        bf16x8 k0 = *reinterpret_cast<const bf16x8*>(k0base + krow * 32);
        bf16x8 k1 = *reinterpret_cast<const bf16x8*>(k1base + krow * 32);
        acc[f] = MFMA16(k0, aq0, acc[f]);       // A = K rows, B = Q rows -> S^T
        acc[f] = MFMA16(k1, aq1, acc[f]);
        f32x4 bv = *reinterpret_cast<const f32x4*>(brow + f * 16);
        acc[f] += bv;
    }

    float* smaxp = reinterpret_cast<float*>(&plds[0][0][0]);   // 64 f32 (aliased)
    float* ssump = smaxp + 64;                                 // 64 f32 (aliased)

    // ---- row max: in-lane over 64 values, shuffle xor16/32, LDS cross-wave
    f32x4 m4 = acc[0];
#pragma unroll
    for (int f = 1; f < 16; ++f) {
#pragma unroll
        for (int r = 0; r < 4; ++r) m4[r] = fmaxf(m4[r], acc[f][r]);
    }
    float mx = fmaxf(fmaxf(m4[0], m4[1]), fmaxf(m4[2], m4[3]));
    mx = fmaxf(mx, __shfl_xor(mx, 16));
    mx = fmaxf(mx, __shfl_xor(mx, 32));
    if (lane < 16) smaxp[wave * 16 + lr] = mx;
    __syncthreads();
    const float gm = fmaxf(fmaxf(smaxp[lr], smaxp[16 + lr]),
                           fmaxf(smaxp[32 + lr], smaxp[48 + lr]));

    // ---- exp once + row sum
    f32x4 s4 = {0.f, 0.f, 0.f, 0.f};
#pragma unroll
    for (int f = 0; f < 16; ++f) {
#pragma unroll
        for (int r = 0; r < 4; ++r) {
            const float e = __expf(acc[f][r] - gm);
            acc[f][r] = e;
            s4[r] += e;
        }
    }
    float sm = (s4[0] + s4[1]) + (s4[2] + s4[3]);
    sm += __shfl_xor(sm, 16);
    sm += __shfl_xor(sm, 32);
    if (lane < 16) ssump[wave * 16 + lr] = sm;
    __syncthreads();
    const float invl = 1.0f / (ssump[lr] + ssump[16 + lr] + ssump[32 + lr] + ssump[48 + lr]);
    __syncthreads();   // guard: smax/ssum alias the P region written below

    // ---- write normalized attn (f32x4) + pack P to swizzled LDS (b64)
    float* orow = attn + ((size_t)bh << 20) + (size_t)(m0 + lr) * 1024 + c0 + lg * 4;
    char* pw = reinterpret_cast<char*>(&plds[wave][0][0]);
    const int swz = (lr & 7) << 4;
#pragma unroll
    for (int f = 0; f < 16; ++f) {
        f32x4 v = acc[f];
#pragma unroll
        for (int r = 0; r < 4; ++r) v[r] *= invl;
        *reinterpret_cast<f32x4*>(orow + f * 16) = v;
        bf16x4 pb = { (bf16_t)v[0], (bf16_t)v[1], (bf16_t)v[2], (bf16_t)v[3] };
        *reinterpret_cast<bf16x4*>(pw + lr * 512 + ((f * 32 + lg * 8) ^ swz)) = pb;
    }
    // (no barrier: plds[wave] written and read only by this wave)

    // ---- PV over this wave's 256 cols: A = P (LDS), B = vp k-tiles (1KB contig)
    const bf16_t* vpb = vp + ((size_t)bh << 16) + (size_t)(wave * 8) * 2048 + lg * 8;
    f32x4 cacc[4];
#pragma unroll
    for (int f2 = 0; f2 < 4; ++f2) cacc[f2] = (f32x4){0.f, 0.f, 0.f, 0.f};
#pragma unroll
    for (int ks = 0; ks < 8; ++ks) {
        bf16x8 pa = *reinterpret_cast<const bf16x8*>(pw + lr * 512 + ((ks * 64 + lg * 16) ^ swz));
        const bf16_t* vk = vpb + ks * 2048;
#pragma unroll
        for (int f2 = 0; f2 < 4; ++f2) {
            bf16x8 vf = *reinterpret_cast<const bf16x8*>(vk + (f2 * 16 + lr) * 32);
            cacc[f2] = MFMA16(pa, vf, cacc[f2]);
        }
    }
    __syncthreads();   // all waves done with P tiles; re-alias as cred

    // ---- cross-wave ctx reduce via LDS (aliases plds)
    float* cred = reinterpret_cast<float*>(&plds[0][0][0]);    // [4][16][64] f32
#pragma unroll
    for (int f2 = 0; f2 < 4; ++f2)
#pragma unroll
        for (int r = 0; r < 4; ++r)
            cred[wave * 1024 + (lg * 4 + r) * 64 + f2 * 16 + lr] = cacc[f2][r];
    __syncthreads();
    const int row_l = wave * 4 + lg;
    const int dk0 = lr * 4;
    f32x4 s0 = *reinterpret_cast<const f32x4*>(&cred[0 * 1024 + row_l * 64 + dk0]);
    f32x4 s1 = *reinterpret_cast<const f32x4*>(&cred[1 * 1024 + row_l * 64 + dk0]);
    f32x4 s2 = *reinterpret_cast<const f32x4*>(&cred[2 * 1024 + row_l * 64 + dk0]);
    f32x4 s3 = *reinterpret_cast<const f32x4*>(&cred[3 * 1024 + row_l * 64 + dk0]);
    f32x4 st = (s0 + s1) + (s2 + s3);
    bf16x4 o4 = { (bf16_t)st[0], (bf16_t)st[1], (bf16_t)st[2], (bf16_t)st[3] };
    *reinterpret_cast<bf16x4*>(
        &ctxb[(size_t)(b * 1024 + m0 + row_l) * 1024 + h * 64 + dk0]) = o4;
}

// ---------------------------------------------------------------------- launcher
extern "C" void kernel_launch(void* const* d_in, const int* in_sizes, int n_in,
                              void* d_out, int out_size, void* d_ws, size_t ws_size,
                              hipStream_t stream) {
    const float* x    = (const float*)d_in[0];
    const float* bias = (const float*)d_in[1];
    const float* Wq   = (const float*)d_in[2];
    const float* Wk   = (const float*)d_in[3];
    const float* Wv   = (const float*)d_in[4];
    const float* Wo   = (const float*)d_in[5];
    float* out  = (float*)d_out;
    float* attn = out + (size_t)4 * 1024 * 1024;

    char* ws = (char*)d_ws;
    bf16_t* xb   = (bf16_t*)(ws);                      //  8 MB [4096,1024]
    bf16_t* wT   = (bf16_t*)(ws + ((size_t)8 << 20));  //  8 MB 4x [1024,1024] transposed
    bf16_t* qhp  = (bf16_t*)(ws + ((size_t)16 << 20)); //  8 MB Q/8 packed half-planes
    bf16_t* khp  = (bf16_t*)(ws + ((size_t)24 << 20)); //  8 MB K packed half-planes
    bf16_t* vp   = (bf16_t*)(ws + ((size_t)32 << 20)); //  8 MB V packed k-tiles
    bf16_t* ctxb = (bf16_t*)(ws + ((size_t)40 << 20)); //  8 MB ctx [B,S,D]
    bf16_t* wqT = wT;
    bf16_t* wkT = wT + ((size_t)1 << 20);
    bf16_t* wvT = wT + ((size_t)2 << 20);
    bf16_t* woT = wT + ((size_t)3 << 20);

    cast_f32_bf16<<<dim3(4096), dim3(256), 0, stream>>>(x, xb, 1024 * 1024);
    transpose_cast_w<<<dim3(32, 32, 4), dim3(32, 32), 0, stream>>>(Wq, Wk, Wv, Wo, wT);

    gemm_tile<0><<<dim3(32, 8), dim3(256), 0, stream>>>(xb, wqT, qhp);
    gemm_tile<1><<<dim3(32, 8), dim3(256), 0, stream>>>(xb, wkT, khp);
    gemm_tile<2><<<dim3(32, 8), dim3(256), 0, stream>>>(xb, wvT, vp);

    fused_attn<<<dim3(4096), dim3(256), 0, stream>>>(qhp, khp, vp, bias, attn, ctxb);

    gemm_tile<3><<<dim3(32, 8), dim3(256), 0, stream>>>(ctxb, woT, out);
}

// Round 6
// 218.505 us; speedup vs baseline: 1.3756x; 1.1114x over previous
//
#include <hip/hip_runtime.h>
#include <hip/hip_bf16.h>

// MHA forward: B=4, S=1024, D=1024, H=16, DK=64
// outputs: out [4,1024,1024] f32, attn [4,16,1024,1024] f32 (concat in d_out)
//
// Packed operand layouts for the fused kernel (all bf16):
//   qhp/khp: [bh][half=dk/32][s][32]   -> frag loads 1KB contiguous
//   vp:      [bh][kb=s/32][dk][32]     -> PV frag loads 1KB contiguous

typedef __bf16 bf16_t;
typedef __bf16 bf16x4 __attribute__((ext_vector_type(4)));
typedef __bf16 bf16x8 __attribute__((ext_vector_type(8)));
typedef float f32x4 __attribute__((ext_vector_type(4)));

#define MFMA16(a, b, c) __builtin_amdgcn_mfma_f32_16x16x32_bf16(a, b, c, 0, 0, 0)

// ---------------------------------------------------------------- cast x -> bf16
__global__ __launch_bounds__(256) void cast_f32_bf16(const float* __restrict__ in,
                                                     bf16_t* __restrict__ out, int n4) {
    int i = blockIdx.x * blockDim.x + threadIdx.x;
    if (i >= n4) return;
    float4 v = reinterpret_cast<const float4*>(in)[i];
    bf16x4 o = { (bf16_t)v.x, (bf16_t)v.y, (bf16_t)v.z, (bf16_t)v.w };
    reinterpret_cast<bf16x4*>(out)[i] = o;
}

// ------------------------------------------- transpose + cast the 4 weight matrices
__global__ __launch_bounds__(1024) void transpose_cast_w(const float* __restrict__ w0,
                                                         const float* __restrict__ w1,
                                                         const float* __restrict__ w2,
                                                         const float* __restrict__ w3,
                                                         bf16_t* __restrict__ wt) {
    __shared__ float tile[32][33];
    const float* src = (blockIdx.z == 0) ? w0 : (blockIdx.z == 1) ? w1
                     : (blockIdx.z == 2) ? w2 : w3;
    bf16_t* dst = wt + (size_t)blockIdx.z * 1024 * 1024;
    int r0 = blockIdx.y * 32, c0 = blockIdx.x * 32;
    tile[threadIdx.y][threadIdx.x] = src[(size_t)(r0 + threadIdx.y) * 1024 + c0 + threadIdx.x];
    __syncthreads();
    dst[(size_t)(c0 + threadIdx.y) * 1024 + r0 + threadIdx.x] = (bf16_t)tile[threadIdx.x][threadIdx.y];
}

// ------------------------------------------------------- GEMM core (128x128 tile)
// block = 256 threads = 4 waves (2x2), each wave 64x64 output (4x4 frags)
#define GEMM_BODY(A, BT)                                                                 \
    __shared__ bf16_t As[128 * 32];                                                      \
    __shared__ bf16_t Bs[128 * 32];                                                      \
    const int tid = threadIdx.x;                                                         \
    const int lane = tid & 63, wave = tid >> 6;                                          \
    const int lr = lane & 15, lg = lane >> 4;                                            \
    const int m_base = blockIdx.x * 128, n_base = blockIdx.y * 128;                      \
    const int wm = (wave >> 1) * 64, wn = (wave & 1) * 64;                               \
    const int srow = tid >> 1;                                                           \
    const int sl0 = (tid & 1) * 2;                                                       \
    const int sl1 = sl0 + 1;                                                             \
    const int off0 = srow * 32 + ((sl0 ^ ((srow >> 1) & 3)) * 8);                        \
    const int off1 = srow * 32 + ((sl1 ^ ((srow >> 1) & 3)) * 8);                        \
    const bf16_t* aptr = (A) + (size_t)(m_base + srow) * 1024 + sl0 * 8;                 \
    const bf16_t* bptr = (BT) + (size_t)(n_base + srow) * 1024 + sl0 * 8;                \
    bf16x8 ra0 = *reinterpret_cast<const bf16x8*>(aptr);                                 \
    bf16x8 ra1 = *reinterpret_cast<const bf16x8*>(aptr + 8);                             \
    bf16x8 rb0 = *reinterpret_cast<const bf16x8*>(bptr);                                 \
    bf16x8 rb1 = *reinterpret_cast<const bf16x8*>(bptr + 8);                             \
    f32x4 acc[4][4] = {};                                                                \
    for (int kb = 32; kb <= 1024; kb += 32) {                                            \
        __syncthreads();                                                                 \
        *reinterpret_cast<bf16x8*>(&As[off0]) = ra0;                                     \
        *reinterpret_cast<bf16x8*>(&As[off1]) = ra1;                                     \
        *reinterpret_cast<bf16x8*>(&Bs[off0]) = rb0;                                     \
        *reinterpret_cast<bf16x8*>(&Bs[off1]) = rb1;                                     \
        if (kb < 1024) {                                                                 \
            ra0 = *reinterpret_cast<const bf16x8*>(aptr + kb);                           \
            ra1 = *reinterpret_cast<const bf16x8*>(aptr + kb + 8);                       \
            rb0 = *reinterpret_cast<const bf16x8*>(bptr + kb);                           \
            rb1 = *reinterpret_cast<const bf16x8*>(bptr + kb + 8);                       \
        }                                                                                \
        __syncthreads();                                                                 \
        bf16x8 af[4], bfr[4];                                                            \
        _Pragma("unroll") for (int i = 0; i < 4; ++i) {                                  \
            const int row = wm + i * 16 + lr;                                            \
            af[i] = *reinterpret_cast<const bf16x8*>(                                    \
                &As[row * 32 + ((lg ^ ((row >> 1) & 3)) * 8)]);                          \
        }                                                                                \
        _Pragma("unroll") for (int j = 0; j < 4; ++j) {                                  \
            const int row = wn + j * 16 + lr;                                            \
            bfr[j] = *reinterpret_cast<const bf16x8*>(                                   \
                &Bs[row * 32 + ((lg ^ ((row >> 1) & 3)) * 8)]);                          \
        }                                                                                \
        _Pragma("unroll") for (int i = 0; i < 4; ++i)                                    \
            _Pragma("unroll") for (int j = 0; j < 4; ++j)                                \
                acc[i][j] = MFMA16(af[i], bfr[j], acc[i][j]);                            \
    }

// ---------------------------------------------------- QKV projections, one launch
// blockIdx.z: 0 = Q -> qhp (x0.125), 1 = K -> khp, 2 = V -> vp
__global__ __launch_bounds__(256, 3) void gemm_qkv(const bf16_t* __restrict__ A,
                                                   const bf16_t* __restrict__ wT,
                                                   bf16_t* __restrict__ qhp,
                                                   bf16_t* __restrict__ khp,
                                                   bf16_t* __restrict__ vp) {
    const int z = blockIdx.z;
    const bf16_t* BT = wT + ((size_t)z << 20);
    GEMM_BODY(A, BT)
    bf16_t* dst = (z == 0) ? qhp : (z == 1) ? khp : vp;
    const float scale = (z == 0) ? 0.125f : 1.0f;
#pragma unroll
    for (int i = 0; i < 4; ++i)
#pragma unroll
        for (int j = 0; j < 4; ++j)
#pragma unroll
            for (int r = 0; r < 4; ++r) {
                const int row = m_base + wm + i * 16 + lg * 4 + r;
                const int col = n_base + wn + j * 16 + lr;
                const float v = acc[i][j][r] * scale;
                const int b = row >> 10, s = row & 1023;
                const int h = col >> 6, d = col & 63;
                const size_t bh16 = (size_t)(b * 16 + h) << 16;
                if (z == 2)   // vp[bh][s/32][d][s%32]
                    dst[bh16 + ((s >> 5) << 11) + d * 32 + (s & 31)] = (bf16_t)v;
                else          // qhp/khp[bh][d/32][s][d%32]
                    dst[bh16 + ((d >> 5) << 15) + s * 32 + (d & 31)] = (bf16_t)v;
            }
}

// ------------------------------------------------------------- output projection
__global__ __launch_bounds__(256, 3) void gemm_out(const bf16_t* __restrict__ A,
                                                   const bf16_t* __restrict__ BT,
                                                   float* __restrict__ out) {
    GEMM_BODY(A, BT)
#pragma unroll
    for (int i = 0; i < 4; ++i)
#pragma unroll
        for (int j = 0; j < 4; ++j)
#pragma unroll
            for (int r = 0; r < 4; ++r) {
                const int row = m_base + wm + i * 16 + lg * 4 + r;
                const int col = n_base + wn + j * 16 + lr;
                out[(size_t)row * 1024 + col] = acc[i][j][r];
            }
}

// --------------------------------------- fused scores+bias+softmax+attn-write+PV
// SWAPPED QK^T: S^T = mfma(K, Q); lane owns ONE q-row (q = lane&15), cols
// k = f*16 + lg*4 + reg. launch_bounds(256,2) -> 256-reg budget: batch-issue
// ALL fragment loads into register arrays (kf[16] pairs = 128 VGPRs in flight,
// then vf[8][4] after acc dies) so memory latency is exposed ~once per phase
// instead of per-load. All load offsets are compile-time immediates.
__global__ __launch_bounds__(256, 2) void fused_attn(const bf16_t* __restrict__ qhp,
                                                     const bf16_t* __restrict__ khp,
                                                     const bf16_t* __restrict__ vp,
                                                     const float* __restrict__ bias,
                                                     float* __restrict__ attn,
                                                     bf16_t* __restrict__ ctxb) {
    __shared__ bf16_t plds[4][16][256];     // 32768 B: per-wave 16x256 P tile
    const int lane = threadIdx.x & 63;
    const int wave = threadIdx.x >> 6;
    const int lr = lane & 15, lg = lane >> 4;

    // decode: g&7 = xcd slot; per-xcd order: b fastest (shares bias tile), then qt
    const int g = blockIdx.x;
    const int j = g >> 3;
    const int h = (g & 7) + 8 * (j >> 8);
    const int qt = (j & 255) >> 2;
    const int b = j & 3;
    const int bh = b * 16 + h;
    const int m0 = qt * 16;

    // Q B-frag: lane holds Q[m0+lr][dk lg*8..+7] per half-plane
    const bf16_t* qbase = qhp + ((size_t)bh << 16);
    const bf16x8 aq0 = *reinterpret_cast<const bf16x8*>(qbase + (m0 + lr) * 32 + lg * 8);
    const bf16x8 aq1 = *reinterpret_cast<const bf16x8*>(qbase + 32768 + (m0 + lr) * 32 + lg * 8);

    const int c0 = wave * 256;              // this wave's k-col slice
    // per-lane K base; per-f offsets are +1024B immediates
    const bf16_t* kp0 = khp + ((size_t)bh << 16) + (size_t)(c0 + lr) * 32 + lg * 8;
    const float* brow = bias + ((size_t)h << 20) + (size_t)(m0 + lr) * 1024 + c0 + lg * 4;

    // ---- phase 1a: issue ALL K loads (32 x b128 in flight)
    bf16x8 kf0[16], kf1[16];
#pragma unroll
    for (int f = 0; f < 16; ++f) {
        kf0[f] = *reinterpret_cast<const bf16x8*>(kp0 + f * 512);
        kf1[f] = *reinterpret_cast<const bf16x8*>(kp0 + 32768 + f * 512);
    }
    // ---- phase 1b: QK^T (swapped): acc[f][r] = S[q=m0+lr][k=c0+f*16+lg*4+r]
    f32x4 acc[16];
#pragma unroll
    for (int f = 0; f < 16; ++f) {
        const f32x4 z4 = {0.f, 0.f, 0.f, 0.f};
        acc[f] = MFMA16(kf0[f], aq0, z4);
        acc[f] = MFMA16(kf1[f], aq1, acc[f]);
    }
    // ---- phase 1c: bias (16 x f32x4, all offsets immediate)
#pragma unroll
    for (int f = 0; f < 16; ++f) {
        f32x4 bv = *reinterpret_cast<const f32x4*>(brow + f * 16);
        acc[f] += bv;
    }

    float* smaxp = reinterpret_cast<float*>(&plds[0][0][0]);   // 64 f32 (aliased)
    float* ssump = smaxp + 64;                                 // 64 f32 (aliased)

    // ---- row max: in-lane over 64 values, shuffle xor16/32, LDS cross-wave
    f32x4 m4 = acc[0];
#pragma unroll
    for (int f = 1; f < 16; ++f) {
#pragma unroll
        for (int r = 0; r < 4; ++r) m4[r] = fmaxf(m4[r], acc[f][r]);
    }
    float mx = fmaxf(fmaxf(m4[0], m4[1]), fmaxf(m4[2], m4[3]));
    mx = fmaxf(mx, __shfl_xor(mx, 16));
    mx = fmaxf(mx, __shfl_xor(mx, 32));
    if (lane < 16) smaxp[wave * 16 + lr] = mx;
    __syncthreads();
    const float gm = fmaxf(fmaxf(smaxp[lr], smaxp[16 + lr]),
                           fmaxf(smaxp[32 + lr], smaxp[48 + lr]));

    // ---- exp once + row sum
    f32x4 s4 = {0.f, 0.f, 0.f, 0.f};
#pragma unroll
    for (int f = 0; f < 16; ++f) {
#pragma unroll
        for (int r = 0; r < 4; ++r) {
            const float e = __expf(acc[f][r] - gm);
            acc[f][r] = e;
            s4[r] += e;
        }
    }
    float sm = (s4[0] + s4[1]) + (s4[2] + s4[3]);
    sm += __shfl_xor(sm, 16);
    sm += __shfl_xor(sm, 32);
    if (lane < 16) ssump[wave * 16 + lr] = sm;
    __syncthreads();
    const float invl = 1.0f / (ssump[lr] + ssump[16 + lr] + ssump[32 + lr] + ssump[48 + lr]);
    __syncthreads();   // guard: smax/ssum alias the P region written below

    // ---- issue ALL V loads early (32 x b128 in flight through the store phase)
    const bf16_t* vpb = vp + ((size_t)bh << 16) + (size_t)(wave * 8) * 2048 + lr * 32 + lg * 8;
    bf16x8 vf[8][4];
#pragma unroll
    for (int ks = 0; ks < 8; ++ks)
#pragma unroll
        for (int f2 = 0; f2 < 4; ++f2)
            vf[ks][f2] = *reinterpret_cast<const bf16x8*>(vpb + ks * 2048 + f2 * 512);

    // ---- write normalized attn (f32x4, offsets immediate) + pack P to LDS
    float* orow = attn + ((size_t)bh << 20) + (size_t)(m0 + lr) * 1024 + c0 + lg * 4;
    char* pw = reinterpret_cast<char*>(&plds[wave][0][0]);
    const int swz = (lr & 7) << 4;
#pragma unroll
    for (int f = 0; f < 16; ++f) {
        f32x4 v = acc[f];
#pragma unroll
        for (int r = 0; r < 4; ++r) v[r] *= invl;
        *reinterpret_cast<f32x4*>(orow + f * 16) = v;
        bf16x4 pb = { (bf16_t)v[0], (bf16_t)v[1], (bf16_t)v[2], (bf16_t)v[3] };
        *reinterpret_cast<bf16x4*>(pw + lr * 512 + ((f * 32 + lg * 8) ^ swz)) = pb;
    }
    // (no barrier: plds[wave] written and read only by this wave)

    // ---- PV: A = P (LDS), B = vf (regs). 8 ds_read_b128 + 32 MFMA
    f32x4 cacc[4];
#pragma unroll
    for (int f2 = 0; f2 < 4; ++f2) cacc[f2] = (f32x4){0.f, 0.f, 0.f, 0.f};
#pragma unroll
    for (int ks = 0; ks < 8; ++ks) {
        bf16x8 pa = *reinterpret_cast<const bf16x8*>(pw + lr * 512 + ((ks * 64 + lg * 16) ^ swz));
#pragma unroll
        for (int f2 = 0; f2 < 4; ++f2)
            cacc[f2] = MFMA16(pa, vf[ks][f2], cacc[f2]);
    }
    __syncthreads();   // all waves done with P tiles; re-alias as cred

    // ---- cross-wave ctx reduce via LDS (aliases plds)
    float* cred = reinterpret_cast<float*>(&plds[0][0][0]);    // [4][16][64] f32
#pragma unroll
    for (int f2 = 0; f2 < 4; ++f2)
#pragma unroll
        for (int r = 0; r < 4; ++r)
            cred[wave * 1024 + (lg * 4 + r) * 64 + f2 * 16 + lr] = cacc[f2][r];
    __syncthreads();
    const int row_l = wave * 4 + lg;
    const int dk0 = lr * 4;
    f32x4 s0 = *reinterpret_cast<const f32x4*>(&cred[0 * 1024 + row_l * 64 + dk0]);
    f32x4 s1 = *reinterpret_cast<const f32x4*>(&cred[1 * 1024 + row_l * 64 + dk0]);
    f32x4 s2 = *reinterpret_cast<const f32x4*>(&cred[2 * 1024 + row_l * 64 + dk0]);
    f32x4 s3 = *reinterpret_cast<const f32x4*>(&cred[3 * 1024 + row_l * 64 + dk0]);
    f32x4 st = (s0 + s1) + (s2 + s3);
    bf16x4 o4 = { (bf16_t)st[0], (bf16_t)st[1], (bf16_t)st[2], (bf16_t)st[3] };
    *reinterpret_cast<bf16x4*>(
        &ctxb[(size_t)(b * 1024 + m0 + row_l) * 1024 + h * 64 + dk0]) = o4;
}

// ---------------------------------------------------------------------- launcher
extern "C" void kernel_launch(void* const* d_in, const int* in_sizes, int n_in,
                              void* d_out, int out_size, void* d_ws, size_t ws_size,
                              hipStream_t stream) {
    const float* x    = (const float*)d_in[0];
    const float* bias = (const float*)d_in[1];
    const float* Wq   = (const float*)d_in[2];
    const float* Wk   = (const float*)d_in[3];
    const float* Wv   = (const float*)d_in[4];
    const float* Wo   = (const float*)d_in[5];
    float* out  = (float*)d_out;
    float* attn = out + (size_t)4 * 1024 * 1024;

    char* ws = (char*)d_ws;
    bf16_t* xb   = (bf16_t*)(ws);                      //  8 MB [4096,1024]
    bf16_t* wT   = (bf16_t*)(ws + ((size_t)8 << 20));  //  8 MB 4x [1024,1024] transposed
    bf16_t* qhp  = (bf16_t*)(ws + ((size_t)16 << 20)); //  8 MB Q/8 packed half-planes
    bf16_t* khp  = (bf16_t*)(ws + ((size_t)24 << 20)); //  8 MB K packed half-planes
    bf16_t* vp   = (bf16_t*)(ws + ((size_t)32 << 20)); //  8 MB V packed k-tiles
    bf16_t* ctxb = (bf16_t*)(ws + ((size_t)40 << 20)); //  8 MB ctx [B,S,D]
    bf16_t* woT = wT + ((size_t)3 << 20);

    cast_f32_bf16<<<dim3(4096), dim3(256), 0, stream>>>(x, xb, 1024 * 1024);
    transpose_cast_w<<<dim3(32, 32, 4), dim3(32, 32), 0, stream>>>(Wq, Wk, Wv, Wo, wT);

    gemm_qkv<<<dim3(32, 8, 3), dim3(256), 0, stream>>>(xb, wT, qhp, khp, vp);

    fused_attn<<<dim3(4096), dim3(256), 0, stream>>>(qhp, khp, vp, bias, attn, ctxb);

    gemm_out<<<dim3(32, 8), dim3(256), 0, stream>>>(ctxb, woT, out);
}